// Round 5
// baseline (208.577 us; speedup 1.0000x reference)
//
#include <hip/hip_runtime.h>

typedef __attribute__((ext_vector_type(8))) short short8;
typedef __attribute__((ext_vector_type(4))) float f32x4;

#define S_    2048
#define DI    1024
#define DQK   512
#define DV    512
#define NTOK  8192   // 4 * 2048

// async global->LDS DMA, 16 B/lane (global_load_lds_dwordx4)
#define GLL(gp, lp) __builtin_amdgcn_global_load_lds( \
    (const __attribute__((address_space(1))) unsigned int*)(gp), \
    (__attribute__((address_space(3))) unsigned int*)(lp), 16, 0, 0)

static __device__ __forceinline__ unsigned short f2bf(float f) {
  unsigned int u = __float_as_uint(f);
  u += 0x7fffu + ((u >> 16) & 1u);          // RNE
  return (unsigned short)(u >> 16);
}

// ---------- fp32 -> bf16 convert, 8 elems/thread ----------
__global__ void conv_x_kernel(const float* __restrict__ x,
                              unsigned short* __restrict__ xb, int n) {
  int idx = (blockIdx.x * 256 + threadIdx.x) * 8;
  if (idx >= n) return;
  const float4* p = (const float4*)(x + idx);
  float4 f0 = p[0], f1 = p[1];
  uint4 o;
  o.x = (unsigned)f2bf(f0.x) | ((unsigned)f2bf(f0.y) << 16);
  o.y = (unsigned)f2bf(f0.z) | ((unsigned)f2bf(f0.w) << 16);
  o.z = (unsigned)f2bf(f1.x) | ((unsigned)f2bf(f1.y) << 16);
  o.w = (unsigned)f2bf(f1.z) | ((unsigned)f2bf(f1.w) << 16);
  *(uint4*)(xb + idx) = o;
}

// ---------- W transpose-convert; also zeroes the rowsum buffer ----------
__global__ void conv_wT_kernel(const float* __restrict__ W0, const float* __restrict__ W1,
                               const float* __restrict__ W2,
                               unsigned short* __restrict__ T0, unsigned short* __restrict__ T1,
                               unsigned short* __restrict__ T2,
                               float* __restrict__ rowsum) {
  __shared__ float tile[32][33];
  int mat = blockIdx.z;
  if (mat == 0 && blockIdx.x == 0)
    rowsum[blockIdx.y * 256 + threadIdx.x] = 0.f;   // 32*256 = 8192 rows
  const float* W = (mat == 0) ? W0 : (mat == 1) ? W1 : W2;
  unsigned short* T = (mat == 0) ? T0 : (mat == 1) ? T1 : T2;
  int n0 = blockIdx.x * 32, k0 = blockIdx.y * 32;
  int c = threadIdx.x & 31, r0 = threadIdx.x >> 5;
  for (int i = 0; i < 4; ++i) {
    int kk = r0 + i * 8;
    tile[kk][c] = W[(k0 + kk) * DQK + n0 + c];
  }
  __syncthreads();
  for (int i = 0; i < 4; ++i) {
    int nn = r0 + i * 8;
    T[(n0 + nn) * DI + k0 + c] = f2bf(tile[c][nn]);
  }
}

// ---------- m97-style 128x128 GEMM-BT core (used by s_exp) ----------
__device__ __forceinline__ void gemm_core_128x128(
    const unsigned short* __restrict__ A, const unsigned short* __restrict__ B,
    int lda, int ldb, int K, int m0, int n0,
    unsigned short* As, unsigned short* Bs, f32x4 (&acc)[4][4]) {
  int tid = threadIdx.x, lane = tid & 63, wv = tid >> 6;
  int quad = lane >> 4, l16 = lane & 15;
  int wm = wv >> 1, wn = wv & 1;
  int r0 = wv * 32 + (lane >> 2), c8 = (lane & 3) * 8;
  const unsigned short* ga0 = A + (size_t)(m0 + r0) * lda + c8;
  const unsigned short* ga1 = ga0 + (size_t)16 * lda;
  const unsigned short* gb0 = B + (size_t)(n0 + r0) * ldb + c8;
  const unsigned short* gb1 = gb0 + (size_t)16 * ldb;
  unsigned short* la0 = As + (wv * 32) * 32;   // wave-uniform LDS dests
  unsigned short* la1 = la0 + 16 * 32;
  unsigned short* lb0 = Bs + (wv * 32) * 32;
  unsigned short* lb1 = lb0 + 16 * 32;
#pragma unroll
  for (int i = 0; i < 4; ++i)
#pragma unroll
    for (int j = 0; j < 4; ++j) acc[i][j] = (f32x4){0.f, 0.f, 0.f, 0.f};

  for (int k0 = 0; k0 < K; k0 += 32) {
    __syncthreads();
    GLL(ga0 + k0, la0);
    GLL(ga1 + k0, la1);
    GLL(gb0 + k0, lb0);
    GLL(gb1 + k0, lb1);
    __syncthreads();
    short8 af[4], bf[4];
#pragma unroll
    for (int t = 0; t < 4; ++t) {
      af[t] = *(const short8*)(As + (wm * 64 + t * 16 + l16) * 32 + quad * 8);
      bf[t] = *(const short8*)(Bs + (wn * 64 + t * 16 + l16) * 32 + quad * 8);
    }
#pragma unroll
    for (int tm = 0; tm < 4; ++tm)
#pragma unroll
      for (int tn = 0; tn < 4; ++tn)
        acc[tm][tn] = __builtin_amdgcn_mfma_f32_16x16x32_bf16(af[tm], bf[tn], acc[tm][tn], 0, 0, 0);
  }
}

// ---------- QKV projection, 128x64 tiles (6 blocks/CU) ----------
__global__ __launch_bounds__(256, 4) void qkv_dma_kernel(
    const unsigned short* __restrict__ xb,
    const unsigned short* __restrict__ wqt, const unsigned short* __restrict__ wkt,
    const unsigned short* __restrict__ wvt,
    const float* __restrict__ bq, const float* __restrict__ bk, const float* __restrict__ bv,
    unsigned short* __restrict__ qo, unsigned short* __restrict__ ko,
    unsigned short* __restrict__ vto) {
  __shared__ unsigned short As[128 * 32];   // 8 KB
  __shared__ unsigned short Bs[64 * 32];    // 4 KB
  int mat = blockIdx.z;
  const unsigned short* wt = (mat == 0) ? wqt : (mat == 1) ? wkt : wvt;
  const float* bias = (mat == 0) ? bq : (mat == 1) ? bk : bv;
  float oscale = (mat == 0) ? 0.04419417382415922f : 1.0f;  // fold 1/sqrt(512) into q
  int m0 = blockIdx.y * 128, n0 = blockIdx.x * 64;
  int tid = threadIdx.x, lane = tid & 63, wv = tid >> 6;
  int quad = lane >> 4, l16 = lane & 15;
  int wm = wv >> 1, wn = wv & 1;
  int c8 = (lane & 3) * 8;
  const unsigned short* ga0 = xb + (size_t)(m0 + wv * 32 + (lane >> 2)) * DI + c8;
  const unsigned short* ga1 = ga0 + (size_t)16 * DI;
  const unsigned short* gb0 = wt + (size_t)(n0 + wv * 16 + (lane >> 2)) * DI + c8;
  unsigned short* la0 = As + (wv * 32) * 32;
  unsigned short* la1 = la0 + 16 * 32;
  unsigned short* lb0 = Bs + (wv * 16) * 32;

  f32x4 acc[4][2];
#pragma unroll
  for (int i = 0; i < 4; ++i)
#pragma unroll
    for (int j = 0; j < 2; ++j) acc[i][j] = (f32x4){0.f, 0.f, 0.f, 0.f};

  for (int k0 = 0; k0 < DI; k0 += 32) {
    __syncthreads();
    GLL(ga0 + k0, la0);
    GLL(ga1 + k0, la1);
    GLL(gb0 + k0, lb0);
    __syncthreads();
    short8 af[4], bf[2];
#pragma unroll
    for (int t = 0; t < 4; ++t)
      af[t] = *(const short8*)(As + (wm * 64 + t * 16 + l16) * 32 + quad * 8);
#pragma unroll
    for (int t = 0; t < 2; ++t)
      bf[t] = *(const short8*)(Bs + (wn * 32 + t * 16 + l16) * 32 + quad * 8);
#pragma unroll
    for (int tm = 0; tm < 4; ++tm)
#pragma unroll
      for (int tn = 0; tn < 2; ++tn)
        acc[tm][tn] = __builtin_amdgcn_mfma_f32_16x16x32_bf16(af[tm], bf[tn], acc[tm][tn], 0, 0, 0);
  }

  bool transp = (mat == 2);
  unsigned short* outp = (mat == 0) ? qo : (mat == 1) ? ko : vto;
#pragma unroll
  for (int tn = 0; tn < 2; ++tn) {
    int col = n0 + wn * 32 + tn * 16 + l16;
    float bc = bias[col];
#pragma unroll
    for (int tm = 0; tm < 4; ++tm) {
      int rowb = m0 + wm * 64 + tm * 16 + quad * 4;
      f32x4 a = acc[tm][tn];
      if (!transp) {
        outp[(size_t)(rowb + 0) * DQK + col] = f2bf((a.x + bc) * oscale);
        outp[(size_t)(rowb + 1) * DQK + col] = f2bf((a.y + bc) * oscale);
        outp[(size_t)(rowb + 2) * DQK + col] = f2bf((a.z + bc) * oscale);
        outp[(size_t)(rowb + 3) * DQK + col] = f2bf((a.w + bc) * oscale);
      } else {
        ushort4 pk;
        pk.x = f2bf(a.x + bc); pk.y = f2bf(a.y + bc);
        pk.z = f2bf(a.z + bc); pk.w = f2bf(a.w + bc);
        *(ushort4*)(outp + (size_t)col * NTOK + rowb) = pk;
      }
    }
  }
}

// ---------- S = exp(Q K^T): bf16 e^s out + rowsum atomics ----------
// Flat grid 1024 (4/CU); batch pinned to XCD pair (K/Q per batch fits L2).
// No max-subtraction: |s| <= |q||k|/sqrt(512) ~ 23 -> exp fp32-safe.
__global__ __launch_bounds__(256, 2) void s_exp_kernel(
    const unsigned short* __restrict__ q, const unsigned short* __restrict__ k,
    unsigned short* __restrict__ sp, float* __restrict__ rowsum) {
  __shared__ unsigned short As[128 * 32];
  __shared__ unsigned short Bs[128 * 32];
  int bidx = blockIdx.x;
  int xcd = bidx & 7, b = xcd >> 1;
  int sub = ((bidx >> 3) << 1) | (xcd & 1);   // [0,256): n fastest within XCD
  int m0 = (sub >> 4) * 128, n0 = (sub & 15) * 128;
  f32x4 acc[4][4];
  gemm_core_128x128(q + (size_t)b * S_ * DQK, k + (size_t)b * S_ * DQK,
                    DQK, DQK, DQK, m0, n0, As, Bs, acc);

  int tid = threadIdx.x, lane = tid & 63, wv = tid >> 6;
  int quad = lane >> 4, l16 = lane & 15;
  int wm = wv >> 1, wn = wv & 1;
  unsigned short* Cb = sp + (size_t)b * S_ * S_;
#pragma unroll
  for (int tm = 0; tm < 4; ++tm) {
    int rowb = m0 + wm * 64 + tm * 16 + quad * 4;
    float rs[4] = {0.f, 0.f, 0.f, 0.f};
#pragma unroll
    for (int tn = 0; tn < 4; ++tn) {
      int col = n0 + wn * 64 + tn * 16 + l16;
      f32x4 a = acc[tm][tn];
      float e0 = __expf(a.x), e1 = __expf(a.y), e2 = __expf(a.z), e3 = __expf(a.w);
      Cb[(size_t)(rowb + 0) * S_ + col] = f2bf(e0);
      Cb[(size_t)(rowb + 1) * S_ + col] = f2bf(e1);
      Cb[(size_t)(rowb + 2) * S_ + col] = f2bf(e2);
      Cb[(size_t)(rowb + 3) * S_ + col] = f2bf(e3);
      rs[0] += e0; rs[1] += e1; rs[2] += e2; rs[3] += e3;
    }
    for (int off = 1; off < 16; off <<= 1)
#pragma unroll
      for (int r = 0; r < 4; ++r) rs[r] += __shfl_xor(rs[r], off);
    if (l16 == 0)
#pragma unroll
      for (int r = 0; r < 4; ++r) atomicAdd(rowsum + b * S_ + rowb + r, rs[r]);
  }
}

// ---------- O = (P V) / rowsum: 64x64 tiles -> 1024 blocks (4/CU) ----------
__global__ __launch_bounds__(256, 4) void pv_kernel(
    const unsigned short* __restrict__ sp, const unsigned short* __restrict__ vt,
    const float* __restrict__ rowsum, float* __restrict__ out) {
  __shared__ unsigned short As[64 * 32];    // P tile [m][k], 4 KB
  __shared__ unsigned short Bs[64 * 32];    // V tile [dim][k], 4 KB
  int bidx = blockIdx.x;
  int xcd = bidx & 7, b = xcd >> 1;
  int sub = ((bidx >> 3) << 1) | (xcd & 1);   // [0,256): n fastest within XCD
  int m0 = (sub >> 3) * 64, n0 = (sub & 7) * 64;
  int tid = threadIdx.x, lane = tid & 63, wv = tid >> 6;
  int quad = lane >> 4, l16 = lane & 15;
  int wm = wv >> 1, wn = wv & 1;
  const unsigned short* A = sp + (size_t)b * S_ * S_;
  const unsigned short* B = vt + (size_t)b * S_;          // vt[dim][tok], ld NTOK
  int c8 = (lane & 3) * 8;
  const unsigned short* ga0 = A + (size_t)(m0 + wv * 16 + (lane >> 2)) * S_ + c8;
  const unsigned short* gb0 = B + (size_t)(n0 + wv * 16 + (lane >> 2)) * NTOK + c8;
  unsigned short* la0 = As + (wv * 16) * 32;
  unsigned short* lb0 = Bs + (wv * 16) * 32;
  f32x4 acc[2][2];
#pragma unroll
  for (int i = 0; i < 2; ++i)
#pragma unroll
    for (int j = 0; j < 2; ++j) acc[i][j] = (f32x4){0.f, 0.f, 0.f, 0.f};

  for (int k0 = 0; k0 < S_; k0 += 32) {
    __syncthreads();
    GLL(ga0 + k0, la0);
    GLL(gb0 + k0, lb0);
    __syncthreads();
    short8 af[2], bf[2];
#pragma unroll
    for (int t = 0; t < 2; ++t) {
      af[t] = *(const short8*)(As + (wm * 32 + t * 16 + l16) * 32 + quad * 8);
      bf[t] = *(const short8*)(Bs + (wn * 32 + t * 16 + l16) * 32 + quad * 8);
    }
#pragma unroll
    for (int tm = 0; tm < 2; ++tm)
#pragma unroll
      for (int tn = 0; tn < 2; ++tn)
        acc[tm][tn] = __builtin_amdgcn_mfma_f32_16x16x32_bf16(af[tm], bf[tn], acc[tm][tn], 0, 0, 0);
  }

  float* ob = out + (size_t)b * S_ * DV;
#pragma unroll
  for (int tm = 0; tm < 2; ++tm) {
    int rowb = m0 + wm * 32 + tm * 16 + quad * 4;
    float inv[4];
#pragma unroll
    for (int i = 0; i < 4; ++i) inv[i] = 1.0f / rowsum[b * S_ + rowb + i];
#pragma unroll
    for (int tn = 0; tn < 2; ++tn) {
      int col = n0 + wn * 32 + tn * 16 + l16;
      f32x4 a = acc[tm][tn];
      ob[(size_t)(rowb + 0) * DV + col] = a.x * inv[0];
      ob[(size_t)(rowb + 1) * DV + col] = a.y * inv[1];
      ob[(size_t)(rowb + 2) * DV + col] = a.z * inv[2];
      ob[(size_t)(rowb + 3) * DV + col] = a.w * inv[3];
    }
  }
}

extern "C" void kernel_launch(void* const* d_in, const int* in_sizes, int n_in,
                              void* d_out, int out_size, void* d_ws, size_t ws_size,
                              hipStream_t stream) {
  const float* x  = (const float*)d_in[0];
  const float* Wq = (const float*)d_in[1];
  const float* bq = (const float*)d_in[2];
  const float* Wk = (const float*)d_in[3];
  const float* bk = (const float*)d_in[4];
  const float* Wv = (const float*)d_in[5];
  const float* bv = (const float*)d_in[6];
  float* out = (float*)d_out;

  char* ws = (char*)d_ws;
  unsigned short* xb  = (unsigned short*)(ws);                         // 16 MB: x bf16
  unsigned short* wqt = (unsigned short*)(ws + 16777216);              // 1 MB each: W^T bf16
  unsigned short* wkt = (unsigned short*)(ws + 16777216 + 1048576);
  unsigned short* wvt = (unsigned short*)(ws + 16777216 + 2097152);
  unsigned short* qo  = (unsigned short*)(ws + 19922944);              // 8 MB: q bf16 (pre-scaled)
  unsigned short* ko  = (unsigned short*)(ws + 19922944 + 8388608);    // 8 MB: k bf16
  unsigned short* vto = (unsigned short*)(ws + 19922944 + 16777216);   // 8 MB: v^T bf16
  unsigned short* sp  = (unsigned short*)(ws + 45088768);              // 33.5 MB: e^S bf16
  float* rowsum       = (float*)(ws + 45088768 + 33554432);            // 32 KB

  conv_x_kernel<<<4096, 256, 0, stream>>>(x, xb, NTOK * DI);
  dim3 gw(16, 32, 3);
  conv_wT_kernel<<<gw, 256, 0, stream>>>(Wq, Wk, Wv, wqt, wkt, wvt, rowsum);
  dim3 gq(8, 64, 3);   // 64-wide n-tiles -> 1536 blocks (6/CU)
  qkv_dma_kernel<<<gq, 256, 0, stream>>>(xb, wqt, wkt, wvt, bq, bk, bv, qo, ko, vto);
  s_exp_kernel<<<1024, 256, 0, stream>>>(qo, ko, sp, rowsum);
  pv_kernel<<<1024, 256, 0, stream>>>(sp, vto, rowsum, out);
}

// Round 6
// 185.725 us; speedup vs baseline: 1.1230x; 1.1230x over previous
//
#include <hip/hip_runtime.h>

typedef __attribute__((ext_vector_type(8))) short short8;
typedef __attribute__((ext_vector_type(4))) float f32x4;

#define S_    2048
#define DI    1024
#define DQK   512
#define DV    512
#define NTOK  8192   // 4 * 2048

// async global->LDS DMA, 16 B/lane (global_load_lds_dwordx4)
#define GLL(gp, lp) __builtin_amdgcn_global_load_lds( \
    (const __attribute__((address_space(1))) unsigned int*)(gp), \
    (__attribute__((address_space(3))) unsigned int*)(lp), 16, 0, 0)

static __device__ __forceinline__ unsigned short f2bf(float f) {
  unsigned int u = __float_as_uint(f);
  u += 0x7fffu + ((u >> 16) & 1u);          // RNE
  return (unsigned short)(u >> 16);
}

// ---------- fp32 -> bf16 convert, 8 elems/thread ----------
__global__ void conv_x_kernel(const float* __restrict__ x,
                              unsigned short* __restrict__ xb, int n) {
  int idx = (blockIdx.x * 256 + threadIdx.x) * 8;
  if (idx >= n) return;
  const float4* p = (const float4*)(x + idx);
  float4 f0 = p[0], f1 = p[1];
  uint4 o;
  o.x = (unsigned)f2bf(f0.x) | ((unsigned)f2bf(f0.y) << 16);
  o.y = (unsigned)f2bf(f0.z) | ((unsigned)f2bf(f0.w) << 16);
  o.z = (unsigned)f2bf(f1.x) | ((unsigned)f2bf(f1.y) << 16);
  o.w = (unsigned)f2bf(f1.z) | ((unsigned)f2bf(f1.w) << 16);
  *(uint4*)(xb + idx) = o;
}

// ---------- W transpose-convert; also zeroes the rowsum buffer ----------
__global__ void conv_wT_kernel(const float* __restrict__ W0, const float* __restrict__ W1,
                               const float* __restrict__ W2,
                               unsigned short* __restrict__ T0, unsigned short* __restrict__ T1,
                               unsigned short* __restrict__ T2,
                               float* __restrict__ rowsum) {
  __shared__ float tile[32][33];
  int mat = blockIdx.z;
  if (mat == 0 && blockIdx.x == 0)
    rowsum[blockIdx.y * 256 + threadIdx.x] = 0.f;   // 32*256 = 8192 rows
  const float* W = (mat == 0) ? W0 : (mat == 1) ? W1 : W2;
  unsigned short* T = (mat == 0) ? T0 : (mat == 1) ? T1 : T2;
  int n0 = blockIdx.x * 32, k0 = blockIdx.y * 32;
  int c = threadIdx.x & 31, r0 = threadIdx.x >> 5;
  for (int i = 0; i < 4; ++i) {
    int kk = r0 + i * 8;
    tile[kk][c] = W[(k0 + kk) * DQK + n0 + c];
  }
  __syncthreads();
  for (int i = 0; i < 4; ++i) {
    int nn = r0 + i * 8;
    T[(n0 + nn) * DI + k0 + c] = f2bf(tile[c][nn]);
  }
}

// ---------- m97-style 128x128 GEMM-BT core ----------
__device__ __forceinline__ void gemm_core_128x128(
    const unsigned short* __restrict__ A, const unsigned short* __restrict__ B,
    int lda, int ldb, int K, int m0, int n0,
    unsigned short* As, unsigned short* Bs, f32x4 (&acc)[4][4]) {
  int tid = threadIdx.x, lane = tid & 63, wv = tid >> 6;
  int quad = lane >> 4, l16 = lane & 15;
  int wm = wv >> 1, wn = wv & 1;
  int r0 = wv * 32 + (lane >> 2), c8 = (lane & 3) * 8;
  const unsigned short* ga0 = A + (size_t)(m0 + r0) * lda + c8;
  const unsigned short* ga1 = ga0 + (size_t)16 * lda;
  const unsigned short* gb0 = B + (size_t)(n0 + r0) * ldb + c8;
  const unsigned short* gb1 = gb0 + (size_t)16 * ldb;
  unsigned short* la0 = As + (wv * 32) * 32;   // wave-uniform LDS dests
  unsigned short* la1 = la0 + 16 * 32;
  unsigned short* lb0 = Bs + (wv * 32) * 32;
  unsigned short* lb1 = lb0 + 16 * 32;
#pragma unroll
  for (int i = 0; i < 4; ++i)
#pragma unroll
    for (int j = 0; j < 4; ++j) acc[i][j] = (f32x4){0.f, 0.f, 0.f, 0.f};

  for (int k0 = 0; k0 < K; k0 += 32) {
    __syncthreads();
    GLL(ga0 + k0, la0);
    GLL(ga1 + k0, la1);
    GLL(gb0 + k0, lb0);
    GLL(gb1 + k0, lb1);
    __syncthreads();
    short8 af[4], bf[4];
#pragma unroll
    for (int t = 0; t < 4; ++t) {
      af[t] = *(const short8*)(As + (wm * 64 + t * 16 + l16) * 32 + quad * 8);
      bf[t] = *(const short8*)(Bs + (wn * 64 + t * 16 + l16) * 32 + quad * 8);
    }
#pragma unroll
    for (int tm = 0; tm < 4; ++tm)
#pragma unroll
      for (int tn = 0; tn < 4; ++tn)
        acc[tm][tn] = __builtin_amdgcn_mfma_f32_16x16x32_bf16(af[tm], bf[tn], acc[tm][tn], 0, 0, 0);
  }
}

// ---------- QKV projection, 128x128 tiles, m-stripe -> XCD pinned ----------
// Flat grid 768 (= 3 blocks/CU, all co-resident). xcd = bidx&7 owns m-tiles
// [xcd*8, xcd*8+8) x all 12 (mat,n)-cols: per-XCD set = 2 MB x + 3 MB W ~ L2.
__global__ __launch_bounds__(256, 2) void qkv_dma_kernel(
    const unsigned short* __restrict__ xb,
    const unsigned short* __restrict__ wqt, const unsigned short* __restrict__ wkt,
    const unsigned short* __restrict__ wvt,
    const float* __restrict__ bq, const float* __restrict__ bk, const float* __restrict__ bv,
    unsigned short* __restrict__ qo, unsigned short* __restrict__ ko,
    unsigned short* __restrict__ vto) {
  __shared__ unsigned short As[128 * 32];
  __shared__ unsigned short Bs[128 * 32];
  int bidx = blockIdx.x;
  int xcd = bidx & 7;
  int local = bidx >> 3;          // [0,96)
  int mlocal = local & 7;
  int col12 = local >> 3;         // [0,12) = mat*4 + ntile
  int mat = col12 >> 2;
  int m0 = (xcd * 8 + mlocal) * 128;
  int n0 = (col12 & 3) * 128;
  const unsigned short* wt = (mat == 0) ? wqt : (mat == 1) ? wkt : wvt;
  const float* bias = (mat == 0) ? bq : (mat == 1) ? bk : bv;
  float oscale = (mat == 0) ? 0.04419417382415922f : 1.0f;  // fold 1/sqrt(512) into q
  f32x4 acc[4][4];
  gemm_core_128x128(xb, wt, DI, DI, DI, m0, n0, As, Bs, acc);

  int tid = threadIdx.x, lane = tid & 63, wv = tid >> 6;
  int quad = lane >> 4, l16 = lane & 15;
  int wm = wv >> 1, wn = wv & 1;
  bool transp = (mat == 2);
  unsigned short* outp = (mat == 0) ? qo : (mat == 1) ? ko : vto;
#pragma unroll
  for (int tn = 0; tn < 4; ++tn) {
    int col = n0 + wn * 64 + tn * 16 + l16;
    float bc = bias[col];
#pragma unroll
    for (int tm = 0; tm < 4; ++tm) {
      int rowb = m0 + wm * 64 + tm * 16 + quad * 4;
      f32x4 a = acc[tm][tn];
      if (!transp) {
        outp[(size_t)(rowb + 0) * DQK + col] = f2bf((a.x + bc) * oscale);
        outp[(size_t)(rowb + 1) * DQK + col] = f2bf((a.y + bc) * oscale);
        outp[(size_t)(rowb + 2) * DQK + col] = f2bf((a.z + bc) * oscale);
        outp[(size_t)(rowb + 3) * DQK + col] = f2bf((a.w + bc) * oscale);
      } else {
        ushort4 pk;
        pk.x = f2bf(a.x + bc); pk.y = f2bf(a.y + bc);
        pk.z = f2bf(a.z + bc); pk.w = f2bf(a.w + bc);
        *(ushort4*)(outp + (size_t)col * NTOK + rowb) = pk;
      }
    }
  }
}

// ---------- S = exp(Q K^T): bf16 e^s out + rowsum atomics ----------
// Flat grid 1024 (4/CU); batch pinned to XCD pair (K/Q per batch fits L2).
// No max-subtraction: |s| <= |q||k|/sqrt(512) ~ 23 -> exp fp32-safe.
__global__ __launch_bounds__(256, 2) void s_exp_kernel(
    const unsigned short* __restrict__ q, const unsigned short* __restrict__ k,
    unsigned short* __restrict__ sp, float* __restrict__ rowsum) {
  __shared__ unsigned short As[128 * 32];
  __shared__ unsigned short Bs[128 * 32];
  int bidx = blockIdx.x;
  int xcd = bidx & 7, b = xcd >> 1;
  int sub = ((bidx >> 3) << 1) | (xcd & 1);   // [0,256): n fastest within XCD
  int m0 = (sub >> 4) * 128, n0 = (sub & 15) * 128;
  f32x4 acc[4][4];
  gemm_core_128x128(q + (size_t)b * S_ * DQK, k + (size_t)b * S_ * DQK,
                    DQK, DQK, DQK, m0, n0, As, Bs, acc);

  int tid = threadIdx.x, lane = tid & 63, wv = tid >> 6;
  int quad = lane >> 4, l16 = lane & 15;
  int wm = wv >> 1, wn = wv & 1;
  unsigned short* Cb = sp + (size_t)b * S_ * S_;
#pragma unroll
  for (int tm = 0; tm < 4; ++tm) {
    int rowb = m0 + wm * 64 + tm * 16 + quad * 4;
    float rs[4] = {0.f, 0.f, 0.f, 0.f};
#pragma unroll
    for (int tn = 0; tn < 4; ++tn) {
      int col = n0 + wn * 64 + tn * 16 + l16;
      f32x4 a = acc[tm][tn];
      float e0 = __expf(a.x), e1 = __expf(a.y), e2 = __expf(a.z), e3 = __expf(a.w);
      Cb[(size_t)(rowb + 0) * S_ + col] = f2bf(e0);
      Cb[(size_t)(rowb + 1) * S_ + col] = f2bf(e1);
      Cb[(size_t)(rowb + 2) * S_ + col] = f2bf(e2);
      Cb[(size_t)(rowb + 3) * S_ + col] = f2bf(e3);
      rs[0] += e0; rs[1] += e1; rs[2] += e2; rs[3] += e3;
    }
    for (int off = 1; off < 16; off <<= 1)
#pragma unroll
      for (int r = 0; r < 4; ++r) rs[r] += __shfl_xor(rs[r], off);
    if (l16 == 0)
#pragma unroll
      for (int r = 0; r < 4; ++r) atomicAdd(rowsum + b * S_ + rowb + r, rs[r]);
  }
}

// ---------- O = (P V) / rowsum: 64x64 tiles -> 1024 blocks (4/CU) ----------
__global__ __launch_bounds__(256, 4) void pv_kernel(
    const unsigned short* __restrict__ sp, const unsigned short* __restrict__ vt,
    const float* __restrict__ rowsum, float* __restrict__ out) {
  __shared__ unsigned short As[64 * 32];    // P tile [m][k], 4 KB
  __shared__ unsigned short Bs[64 * 32];    // V tile [dim][k], 4 KB
  int bidx = blockIdx.x;
  int xcd = bidx & 7, b = xcd >> 1;
  int sub = ((bidx >> 3) << 1) | (xcd & 1);   // [0,256): n fastest within XCD
  int m0 = (sub >> 3) * 64, n0 = (sub & 7) * 64;
  int tid = threadIdx.x, lane = tid & 63, wv = tid >> 6;
  int quad = lane >> 4, l16 = lane & 15;
  int wm = wv >> 1, wn = wv & 1;
  const unsigned short* A = sp + (size_t)b * S_ * S_;
  const unsigned short* B = vt + (size_t)b * S_;          // vt[dim][tok], ld NTOK
  int c8 = (lane & 3) * 8;
  const unsigned short* ga0 = A + (size_t)(m0 + wv * 16 + (lane >> 2)) * S_ + c8;
  const unsigned short* gb0 = B + (size_t)(n0 + wv * 16 + (lane >> 2)) * NTOK + c8;
  unsigned short* la0 = As + (wv * 16) * 32;
  unsigned short* lb0 = Bs + (wv * 16) * 32;
  f32x4 acc[2][2];
#pragma unroll
  for (int i = 0; i < 2; ++i)
#pragma unroll
    for (int j = 0; j < 2; ++j) acc[i][j] = (f32x4){0.f, 0.f, 0.f, 0.f};

  for (int k0 = 0; k0 < S_; k0 += 32) {
    __syncthreads();
    GLL(ga0 + k0, la0);
    GLL(gb0 + k0, lb0);
    __syncthreads();
    short8 af[2], bf[2];
#pragma unroll
    for (int t = 0; t < 2; ++t) {
      af[t] = *(const short8*)(As + (wm * 32 + t * 16 + l16) * 32 + quad * 8);
      bf[t] = *(const short8*)(Bs + (wn * 32 + t * 16 + l16) * 32 + quad * 8);
    }
#pragma unroll
    for (int tm = 0; tm < 2; ++tm)
#pragma unroll
      for (int tn = 0; tn < 2; ++tn)
        acc[tm][tn] = __builtin_amdgcn_mfma_f32_16x16x32_bf16(af[tm], bf[tn], acc[tm][tn], 0, 0, 0);
  }

  float* ob = out + (size_t)b * S_ * DV;
#pragma unroll
  for (int tm = 0; tm < 2; ++tm) {
    int rowb = m0 + wm * 32 + tm * 16 + quad * 4;
    float inv[4];
#pragma unroll
    for (int i = 0; i < 4; ++i) inv[i] = 1.0f / rowsum[b * S_ + rowb + i];
#pragma unroll
    for (int tn = 0; tn < 2; ++tn) {
      int col = n0 + wn * 32 + tn * 16 + l16;
      f32x4 a = acc[tm][tn];
      ob[(size_t)(rowb + 0) * DV + col] = a.x * inv[0];
      ob[(size_t)(rowb + 1) * DV + col] = a.y * inv[1];
      ob[(size_t)(rowb + 2) * DV + col] = a.z * inv[2];
      ob[(size_t)(rowb + 3) * DV + col] = a.w * inv[3];
    }
  }
}

extern "C" void kernel_launch(void* const* d_in, const int* in_sizes, int n_in,
                              void* d_out, int out_size, void* d_ws, size_t ws_size,
                              hipStream_t stream) {
  const float* x  = (const float*)d_in[0];
  const float* Wq = (const float*)d_in[1];
  const float* bq = (const float*)d_in[2];
  const float* Wk = (const float*)d_in[3];
  const float* bk = (const float*)d_in[4];
  const float* Wv = (const float*)d_in[5];
  const float* bv = (const float*)d_in[6];
  float* out = (float*)d_out;

  char* ws = (char*)d_ws;
  unsigned short* xb  = (unsigned short*)(ws);                         // 16 MB: x bf16
  unsigned short* wqt = (unsigned short*)(ws + 16777216);              // 1 MB each: W^T bf16
  unsigned short* wkt = (unsigned short*)(ws + 16777216 + 1048576);
  unsigned short* wvt = (unsigned short*)(ws + 16777216 + 2097152);
  unsigned short* qo  = (unsigned short*)(ws + 19922944);              // 8 MB: q bf16 (pre-scaled)
  unsigned short* ko  = (unsigned short*)(ws + 19922944 + 8388608);    // 8 MB: k bf16
  unsigned short* vto = (unsigned short*)(ws + 19922944 + 16777216);   // 8 MB: v^T bf16
  unsigned short* sp  = (unsigned short*)(ws + 45088768);              // 33.5 MB: e^S bf16
  float* rowsum       = (float*)(ws + 45088768 + 33554432);            // 32 KB

  conv_x_kernel<<<4096, 256, 0, stream>>>(x, xb, NTOK * DI);
  dim3 gw(16, 32, 3);
  conv_wT_kernel<<<gw, 256, 0, stream>>>(Wq, Wk, Wv, wqt, wkt, wvt, rowsum);
  qkv_dma_kernel<<<768, 256, 0, stream>>>(xb, wqt, wkt, wvt, bq, bk, bv, qo, ko, vto);
  s_exp_kernel<<<1024, 256, 0, stream>>>(qo, ko, sp, rowsum);
  pv_kernel<<<1024, 256, 0, stream>>>(sp, vto, rowsum, out);
}

// Round 7
// 179.646 us; speedup vs baseline: 1.1610x; 1.0338x over previous
//
#include <hip/hip_runtime.h>

typedef __attribute__((ext_vector_type(8))) short short8;
typedef __attribute__((ext_vector_type(4))) float f32x4;

#define S_    2048
#define DI    1024
#define DQK   512
#define DV    512
#define NTOK  8192   // 4 * 2048

// async global->LDS DMA, 16 B/lane (global_load_lds_dwordx4)
#define GLL(gp, lp) __builtin_amdgcn_global_load_lds( \
    (const __attribute__((address_space(1))) unsigned int*)(gp), \
    (__attribute__((address_space(3))) unsigned int*)(lp), 16, 0, 0)

static __device__ __forceinline__ unsigned short f2bf(float f) {
  unsigned int u = __float_as_uint(f);
  u += 0x7fffu + ((u >> 16) & 1u);          // RNE
  return (unsigned short)(u >> 16);
}

// ---------- fp32 -> bf16 convert, 8 elems/thread ----------
__global__ void conv_x_kernel(const float* __restrict__ x,
                              unsigned short* __restrict__ xb, int n) {
  int idx = (blockIdx.x * 256 + threadIdx.x) * 8;
  if (idx >= n) return;
  const float4* p = (const float4*)(x + idx);
  float4 f0 = p[0], f1 = p[1];
  uint4 o;
  o.x = (unsigned)f2bf(f0.x) | ((unsigned)f2bf(f0.y) << 16);
  o.y = (unsigned)f2bf(f0.z) | ((unsigned)f2bf(f0.w) << 16);
  o.z = (unsigned)f2bf(f1.x) | ((unsigned)f2bf(f1.y) << 16);
  o.w = (unsigned)f2bf(f1.z) | ((unsigned)f2bf(f1.w) << 16);
  *(uint4*)(xb + idx) = o;
}

// ---------- W transpose-convert; also zeroes the rowsum buffer ----------
__global__ void conv_wT_kernel(const float* __restrict__ W0, const float* __restrict__ W1,
                               const float* __restrict__ W2,
                               unsigned short* __restrict__ T0, unsigned short* __restrict__ T1,
                               unsigned short* __restrict__ T2,
                               float* __restrict__ rowsum) {
  __shared__ float tile[32][33];
  int mat = blockIdx.z;
  if (mat == 0 && blockIdx.x == 0)
    rowsum[blockIdx.y * 256 + threadIdx.x] = 0.f;   // 32*256 = 8192 rows
  const float* W = (mat == 0) ? W0 : (mat == 1) ? W1 : W2;
  unsigned short* T = (mat == 0) ? T0 : (mat == 1) ? T1 : T2;
  int n0 = blockIdx.x * 32, k0 = blockIdx.y * 32;
  int c = threadIdx.x & 31, r0 = threadIdx.x >> 5;
  for (int i = 0; i < 4; ++i) {
    int kk = r0 + i * 8;
    tile[kk][c] = W[(k0 + kk) * DQK + n0 + c];
  }
  __syncthreads();
  for (int i = 0; i < 4; ++i) {
    int nn = r0 + i * 8;
    T[(n0 + nn) * DI + k0 + c] = f2bf(tile[c][nn]);
  }
}

// ---------- m97-style 128x128 GEMM-BT core ----------
__device__ __forceinline__ void gemm_core_128x128(
    const unsigned short* __restrict__ A, const unsigned short* __restrict__ B,
    int lda, int ldb, int K, int m0, int n0,
    unsigned short* As, unsigned short* Bs, f32x4 (&acc)[4][4]) {
  int tid = threadIdx.x, lane = tid & 63, wv = tid >> 6;
  int quad = lane >> 4, l16 = lane & 15;
  int wm = wv >> 1, wn = wv & 1;
  int r0 = wv * 32 + (lane >> 2), c8 = (lane & 3) * 8;
  const unsigned short* ga0 = A + (size_t)(m0 + r0) * lda + c8;
  const unsigned short* ga1 = ga0 + (size_t)16 * lda;
  const unsigned short* gb0 = B + (size_t)(n0 + r0) * ldb + c8;
  const unsigned short* gb1 = gb0 + (size_t)16 * ldb;
  unsigned short* la0 = As + (wv * 32) * 32;   // wave-uniform LDS dests
  unsigned short* la1 = la0 + 16 * 32;
  unsigned short* lb0 = Bs + (wv * 32) * 32;
  unsigned short* lb1 = lb0 + 16 * 32;
#pragma unroll
  for (int i = 0; i < 4; ++i)
#pragma unroll
    for (int j = 0; j < 4; ++j) acc[i][j] = (f32x4){0.f, 0.f, 0.f, 0.f};

  for (int k0 = 0; k0 < K; k0 += 32) {
    __syncthreads();
    GLL(ga0 + k0, la0);
    GLL(ga1 + k0, la1);
    GLL(gb0 + k0, lb0);
    GLL(gb1 + k0, lb1);
    __syncthreads();
    short8 af[4], bf[4];
#pragma unroll
    for (int t = 0; t < 4; ++t) {
      af[t] = *(const short8*)(As + (wm * 64 + t * 16 + l16) * 32 + quad * 8);
      bf[t] = *(const short8*)(Bs + (wn * 64 + t * 16 + l16) * 32 + quad * 8);
    }
#pragma unroll
    for (int tm = 0; tm < 4; ++tm)
#pragma unroll
      for (int tn = 0; tn < 4; ++tn)
        acc[tm][tn] = __builtin_amdgcn_mfma_f32_16x16x32_bf16(af[tm], bf[tn], acc[tm][tn], 0, 0, 0);
  }
}

// ---------- QKV projection, 128x128 tiles, m-stripe -> XCD pinned ----------
__global__ __launch_bounds__(256, 2) void qkv_dma_kernel(
    const unsigned short* __restrict__ xb,
    const unsigned short* __restrict__ wqt, const unsigned short* __restrict__ wkt,
    const unsigned short* __restrict__ wvt,
    const float* __restrict__ bq, const float* __restrict__ bk, const float* __restrict__ bv,
    unsigned short* __restrict__ qo, unsigned short* __restrict__ ko,
    unsigned short* __restrict__ vto) {
  __shared__ unsigned short As[128 * 32];
  __shared__ unsigned short Bs[128 * 32];
  int bidx = blockIdx.x;
  int xcd = bidx & 7;
  int local = bidx >> 3;          // [0,96)
  int mlocal = local & 7;
  int col12 = local >> 3;         // [0,12) = mat*4 + ntile
  int mat = col12 >> 2;
  int m0 = (xcd * 8 + mlocal) * 128;
  int n0 = (col12 & 3) * 128;
  const unsigned short* wt = (mat == 0) ? wqt : (mat == 1) ? wkt : wvt;
  const float* bias = (mat == 0) ? bq : (mat == 1) ? bk : bv;
  float oscale = (mat == 0) ? 0.04419417382415922f : 1.0f;  // fold 1/sqrt(512) into q
  f32x4 acc[4][4];
  gemm_core_128x128(xb, wt, DI, DI, DI, m0, n0, As, Bs, acc);

  int tid = threadIdx.x, lane = tid & 63, wv = tid >> 6;
  int quad = lane >> 4, l16 = lane & 15;
  int wm = wv >> 1, wn = wv & 1;
  bool transp = (mat == 2);
  unsigned short* outp = (mat == 0) ? qo : (mat == 1) ? ko : vto;
#pragma unroll
  for (int tn = 0; tn < 4; ++tn) {
    int col = n0 + wn * 64 + tn * 16 + l16;
    float bc = bias[col];
#pragma unroll
    for (int tm = 0; tm < 4; ++tm) {
      int rowb = m0 + wm * 64 + tm * 16 + quad * 4;
      f32x4 a = acc[tm][tn];
      if (!transp) {
        outp[(size_t)(rowb + 0) * DQK + col] = f2bf((a.x + bc) * oscale);
        outp[(size_t)(rowb + 1) * DQK + col] = f2bf((a.y + bc) * oscale);
        outp[(size_t)(rowb + 2) * DQK + col] = f2bf((a.z + bc) * oscale);
        outp[(size_t)(rowb + 3) * DQK + col] = f2bf((a.w + bc) * oscale);
      } else {
        ushort4 pk;
        pk.x = f2bf(a.x + bc); pk.y = f2bf(a.y + bc);
        pk.z = f2bf(a.z + bc); pk.w = f2bf(a.w + bc);
        *(ushort4*)(outp + (size_t)col * NTOK + rowb) = pk;
      }
    }
  }
}

// ---------- S = exp(Q K^T): bf16 e^s out + rowsum atomics ----------
__global__ __launch_bounds__(256, 2) void s_exp_kernel(
    const unsigned short* __restrict__ q, const unsigned short* __restrict__ k,
    unsigned short* __restrict__ sp, float* __restrict__ rowsum) {
  __shared__ unsigned short As[128 * 32];
  __shared__ unsigned short Bs[128 * 32];
  int bidx = blockIdx.x;
  int xcd = bidx & 7, b = xcd >> 1;
  int sub = ((bidx >> 3) << 1) | (xcd & 1);   // [0,256): n fastest within XCD
  int m0 = (sub >> 4) * 128, n0 = (sub & 15) * 128;
  f32x4 acc[4][4];
  gemm_core_128x128(q + (size_t)b * S_ * DQK, k + (size_t)b * S_ * DQK,
                    DQK, DQK, DQK, m0, n0, As, Bs, acc);

  int tid = threadIdx.x, lane = tid & 63, wv = tid >> 6;
  int quad = lane >> 4, l16 = lane & 15;
  int wm = wv >> 1, wn = wv & 1;
  unsigned short* Cb = sp + (size_t)b * S_ * S_;
#pragma unroll
  for (int tm = 0; tm < 4; ++tm) {
    int rowb = m0 + wm * 64 + tm * 16 + quad * 4;
    float rs[4] = {0.f, 0.f, 0.f, 0.f};
#pragma unroll
    for (int tn = 0; tn < 4; ++tn) {
      int col = n0 + wn * 64 + tn * 16 + l16;
      f32x4 a = acc[tm][tn];
      float e0 = __expf(a.x), e1 = __expf(a.y), e2 = __expf(a.z), e3 = __expf(a.w);
      Cb[(size_t)(rowb + 0) * S_ + col] = f2bf(e0);
      Cb[(size_t)(rowb + 1) * S_ + col] = f2bf(e1);
      Cb[(size_t)(rowb + 2) * S_ + col] = f2bf(e2);
      Cb[(size_t)(rowb + 3) * S_ + col] = f2bf(e3);
      rs[0] += e0; rs[1] += e1; rs[2] += e2; rs[3] += e3;
    }
    for (int off = 1; off < 16; off <<= 1)
#pragma unroll
      for (int r = 0; r < 4; ++r) rs[r] += __shfl_xor(rs[r], off);
    if (l16 == 0)
#pragma unroll
      for (int r = 0; r < 4; ++r) atomicAdd(rowsum + b * S_ + rowb + r, rs[r]);
  }
}

// ---------- O = (P V) / rowsum: 64x64, BK=64, dbuf + XOR-swizzled LDS ----
// phys_chunk = chunk ^ (row&7) -> ds_read_b128 hits 2 lanes/bank (free).
// GLL prefetch of tile k+1 issues after the barrier, overlapping compute(k).
__global__ __launch_bounds__(256, 4) void pv_kernel(
    const unsigned short* __restrict__ sp, const unsigned short* __restrict__ vt,
    const float* __restrict__ rowsum, float* __restrict__ out) {
  __shared__ unsigned short As[2][64 * 64];   // 8 KB per buffer
  __shared__ unsigned short Bs[2][64 * 64];
  int bidx = blockIdx.x;
  int xcd = bidx & 7, b = xcd >> 1;
  int sub = ((bidx >> 3) << 1) | (xcd & 1);   // [0,256): n fastest within XCD
  int m0 = (sub >> 3) * 64, n0 = (sub & 7) * 64;
  int tid = threadIdx.x, lane = tid & 63, wv = tid >> 6;
  int quad = lane >> 4, l16 = lane & 15;
  int wm = wv >> 1, wn = wv & 1;
  const unsigned short* A = sp + (size_t)b * S_ * S_;
  const unsigned short* B = vt + (size_t)b * S_;          // vt[dim][tok], ld NTOK

  // staging: thread t -> row t>>3 (of 32), phys chunk t&7 holds global
  // chunk (t&7)^(row&7); two GLL calls per matrix cover 64 rows.
  int srow = tid >> 3;
  int schunk = (tid & 7) ^ (srow & 7);
  const unsigned short* gA0 = A + (size_t)(m0 + srow) * S_ + schunk * 8;
  const unsigned short* gA1 = A + (size_t)(m0 + 32 + srow) * S_ + schunk * 8;
  const unsigned short* gB0 = B + (size_t)(n0 + srow) * NTOK + schunk * 8;
  const unsigned short* gB1 = B + (size_t)(n0 + 32 + srow) * NTOK + schunk * 8;
  int ldsw0 = (wv * 8) * 64;          // wave-uniform dests
  int ldsw1 = (32 + wv * 8) * 64;

  f32x4 acc[2][2];
#pragma unroll
  for (int i = 0; i < 2; ++i)
#pragma unroll
    for (int j = 0; j < 2; ++j) acc[i][j] = (f32x4){0.f, 0.f, 0.f, 0.f};

  auto stage = [&](int buf, int k0) {
    GLL(gA0 + k0, &As[buf][ldsw0]);
    GLL(gA1 + k0, &As[buf][ldsw1]);
    GLL(gB0 + k0, &Bs[buf][ldsw0]);
    GLL(gB1 + k0, &Bs[buf][ldsw1]);
  };

  stage(0, 0);
  for (int kt = 0; kt < 32; ++kt) {
    int cur = kt & 1;
    __syncthreads();                       // drains cur's GLLs (issued last iter)
    if (kt + 1 < 32) stage(cur ^ 1, (kt + 1) * 64);
#pragma unroll
    for (int ks = 0; ks < 2; ++ks) {
      int pc = ((ks * 4 + quad) ^ (l16 & 7)) * 8;   // swizzled chunk offset
      short8 af[2], bf[2];
#pragma unroll
      for (int t = 0; t < 2; ++t) {
        af[t] = *(const short8*)(&As[cur][(wm * 32 + t * 16 + l16) * 64 + pc]);
        bf[t] = *(const short8*)(&Bs[cur][(wn * 32 + t * 16 + l16) * 64 + pc]);
      }
#pragma unroll
      for (int tm = 0; tm < 2; ++tm)
#pragma unroll
        for (int tn = 0; tn < 2; ++tn)
          acc[tm][tn] = __builtin_amdgcn_mfma_f32_16x16x32_bf16(af[tm], bf[tn], acc[tm][tn], 0, 0, 0);
    }
  }

  float* ob = out + (size_t)b * S_ * DV;
#pragma unroll
  for (int tm = 0; tm < 2; ++tm) {
    int rowb = m0 + wm * 32 + tm * 16 + quad * 4;
    float inv[4];
#pragma unroll
    for (int i = 0; i < 4; ++i) inv[i] = 1.0f / rowsum[b * S_ + rowb + i];
#pragma unroll
    for (int tn = 0; tn < 2; ++tn) {
      int col = n0 + wn * 32 + tn * 16 + l16;
      f32x4 a = acc[tm][tn];
      ob[(size_t)(rowb + 0) * DV + col] = a.x * inv[0];
      ob[(size_t)(rowb + 1) * DV + col] = a.y * inv[1];
      ob[(size_t)(rowb + 2) * DV + col] = a.z * inv[2];
      ob[(size_t)(rowb + 3) * DV + col] = a.w * inv[3];
    }
  }
}

extern "C" void kernel_launch(void* const* d_in, const int* in_sizes, int n_in,
                              void* d_out, int out_size, void* d_ws, size_t ws_size,
                              hipStream_t stream) {
  const float* x  = (const float*)d_in[0];
  const float* Wq = (const float*)d_in[1];
  const float* bq = (const float*)d_in[2];
  const float* Wk = (const float*)d_in[3];
  const float* bk = (const float*)d_in[4];
  const float* Wv = (const float*)d_in[5];
  const float* bv = (const float*)d_in[6];
  float* out = (float*)d_out;

  char* ws = (char*)d_ws;
  unsigned short* xb  = (unsigned short*)(ws);                         // 16 MB: x bf16
  unsigned short* wqt = (unsigned short*)(ws + 16777216);              // 1 MB each: W^T bf16
  unsigned short* wkt = (unsigned short*)(ws + 16777216 + 1048576);
  unsigned short* wvt = (unsigned short*)(ws + 16777216 + 2097152);
  unsigned short* qo  = (unsigned short*)(ws + 19922944);              // 8 MB: q bf16 (pre-scaled)
  unsigned short* ko  = (unsigned short*)(ws + 19922944 + 8388608);    // 8 MB: k bf16
  unsigned short* vto = (unsigned short*)(ws + 19922944 + 16777216);   // 8 MB: v^T bf16
  unsigned short* sp  = (unsigned short*)(ws + 45088768);              // 33.5 MB: e^S bf16
  float* rowsum       = (float*)(ws + 45088768 + 33554432);            // 32 KB

  conv_x_kernel<<<4096, 256, 0, stream>>>(x, xb, NTOK * DI);
  dim3 gw(16, 32, 3);
  conv_wT_kernel<<<gw, 256, 0, stream>>>(Wq, Wk, Wv, wqt, wkt, wvt, rowsum);
  qkv_dma_kernel<<<768, 256, 0, stream>>>(xb, wqt, wkt, wvt, bq, bk, bv, qo, ko, vto);
  s_exp_kernel<<<1024, 256, 0, stream>>>(qo, ko, sp, rowsum);
  pv_kernel<<<1024, 256, 0, stream>>>(sp, vto, rowsum, out);
}